// Round 10
// baseline (411.228 us; speedup 1.0000x reference)
//
#include <hip/hip_runtime.h>

// SIR RK4 trajectory: 500000 rows × 3 states × 50 timesteps, f32.
// Reference quirks replicated exactly:
//   - _sir_eq returns the NEW STATE (x + f(x)), not the derivative.
//   - new = x_ORIGINAL + STEP/6*(k1+2k2+2k3+k4)  (closure over x, not prev).
// Output layout: out[row*150 + t*3 + c].
//
// Round 8: NO LDS — register-buffered direct stores.
//   r6/r7 post-mortem: LDS staging machinery (bank-conflicted ds_writes,
//   ds_read->store dependent sweep, syncthreads, index math) is the prime
//   suspect for the ~2x gap vs the ~55 us write floor; occupancy was capped
//   by LDS (37.5 KiB -> 1 wave/SIMD in r6). Here: each lane owns one row,
//   buffers 4 timesteps (48 B) in registers, emits 6 float2 stores, repeat.
//   Per-lane stores are address-sequential -> every 64B line is fully
//   written within ~1 us by one lane -> L2 merges to full-dirty lines.
//   ~45 VGPR, no LDS -> ~8 waves/SIMD: serial RK4 dep chain fully hidden,
//   stores overlap compute naturally (no phase separation).
//   Failure signal (would mean L2 can't merge scattered 8B stores):
//   FETCH_SIZE +~300MB / regression -> fall back to pipelined LDS staging.

#define BATCH 500000
#define NT    50
#define NF    (NT * 3)   // 150 floats per row
#define BLOCK 256

struct F3 { float s, i, r; };

__device__ __forceinline__ F3 sir_eq(F3 v, float b, float g, float rn) {
    float inf = b * v.s * v.i * rn;
    float rec = g * v.i;
    F3 o;
    o.s = v.s - inf;
    o.i = v.i + inf - rec;
    o.r = v.r + rec;
    return o;
}

__device__ __forceinline__ F3 rk_step(F3 prev, F3 x0, float b, float g) {
    // _sir_eq preserves the component sum, so the four divisor sums are
    // n * {1, 1.05, 1.0525, 1.10525} -> 1 rcp + 3 muls (measured absmax
    // 0.0078 vs threshold 0.0259).
    float n  = prev.s + prev.i + prev.r;
    float r1 = __builtin_amdgcn_rcpf(n);
    float r2 = r1 * 0.952380952f;  // 1/1.05
    float r3 = r1 * 0.950118765f;  // 1/1.0525
    float r4 = r1 * 0.904772676f;  // 1/1.10525

    F3 k1 = sir_eq(prev, b, g, r1);
    F3 a2 = { fmaf(0.05f, k1.s, prev.s), fmaf(0.05f, k1.i, prev.i), fmaf(0.05f, k1.r, prev.r) };
    F3 k2 = sir_eq(a2, b, g, r2);
    F3 a3 = { fmaf(0.05f, k2.s, prev.s), fmaf(0.05f, k2.i, prev.i), fmaf(0.05f, k2.r, prev.r) };
    F3 k3 = sir_eq(a3, b, g, r3);
    F3 a4 = { fmaf(0.10f, k3.s, prev.s), fmaf(0.10f, k3.i, prev.i), fmaf(0.10f, k3.r, prev.r) };
    F3 k4 = sir_eq(a4, b, g, r4);

    const float C = (float)(0.1 / 6.0);
    F3 nw;
    nw.s = fmaf(C, (k1.s + k4.s) + 2.0f * (k2.s + k3.s), x0.s);
    nw.i = fmaf(C, (k1.i + k4.i) + 2.0f * (k2.i + k3.i), x0.i);
    nw.r = fmaf(C, (k1.r + k4.r) + 2.0f * (k2.r + k3.r), x0.r);
    return nw;
}

__global__ __launch_bounds__(BLOCK) void sir_rk4_kernel(
        const float* __restrict__ x,
        const float* __restrict__ beta,
        const float* __restrict__ gamma,
        float* __restrict__ out) {
    const int row = blockIdx.x * BLOCK + threadIdx.x;
    const bool active = row < BATCH;

    const float b = beta[0];
    const float g = gamma[0];

    F3 xv = { 1.0f, 1.0f, 1.0f };             // benign for tail lanes
    if (active) {
        xv.s = x[(size_t)row * 3 + 0];
        xv.i = x[(size_t)row * 3 + 1];
        xv.r = x[(size_t)row * 3 + 2];
    }

    float* orow = out + (size_t)row * NF;     // row base: 600B*row, 8B-aligned

    F3 prev = xv;
    // 13 groups: 12 x 4 timesteps + 1 x 2 timesteps = 50.
    // All loop indices compile-time after unroll -> buf stays in VGPRs (rule #20).
    #pragma unroll
    for (int gi = 0; gi < 13; ++gi) {
        const int nsteps = (gi < 12) ? 4 : 2;
        float buf[12];
        #pragma unroll
        for (int t = 0; t < 4; ++t) {
            if (t >= nsteps) break;
            if (gi == 0 && t == 0) {          // t=0 is x itself
                buf[0] = xv.s; buf[1] = xv.i; buf[2] = xv.r;
            } else {
                prev = rk_step(prev, xv, b, g);
                buf[t * 3 + 0] = prev.s;
                buf[t * 3 + 1] = prev.i;
                buf[t * 3 + 2] = prev.r;
            }
        }
        if (active) {
            #pragma unroll
            for (int j = 0; j < 6; ++j) {
                if (j >= nsteps * 3 / 2) break;
                // dst byte = 600*row + 48*gi + 8*j : 8B-aligned
                *reinterpret_cast<float2*>(orow + gi * 12 + 2 * j) =
                    make_float2(buf[2 * j], buf[2 * j + 1]);
            }
        }
    }
}

extern "C" void kernel_launch(void* const* d_in, const int* in_sizes, int n_in,
                              void* d_out, int out_size, void* d_ws, size_t ws_size,
                              hipStream_t stream) {
    const float* x     = (const float*)d_in[0];
    const float* beta  = (const float*)d_in[1];
    const float* gamma = (const float*)d_in[2];
    float* out = (float*)d_out;

    const int grid = (BATCH + BLOCK - 1) / BLOCK;   // 1954
    sir_rk4_kernel<<<grid, BLOCK, 0, stream>>>(x, beta, gamma, out);
}